// Round 3
// baseline (7085.765 us; speedup 1.0000x reference)
//
#include <hip/hip_runtime.h>

static inline int ceil_div_ll(long long a, long long b) { return (int)((a + b - 1) / b); }

// ---------------- degree / norm ----------------
__global__ void k_fill1(float* p, int n) {
    int t = blockIdx.x * blockDim.x + threadIdx.x;
    if (t < n) p[t] = 1.0f;   // self-loop contributes 1 to in-degree
}

__global__ void k_edge_deg(const int* __restrict__ dst, float* deg, int E) {
    int t = blockIdx.x * blockDim.x + threadIdx.x;
    if (t < E) atomicAdd(&deg[dst[t]], 1.0f);
}

__global__ void k_rsqrt(float* p, int n) {
    int t = blockIdx.x * blockDim.x + threadIdx.x;
    if (t < n) p[t] = rsqrtf(p[t]);
}

// ---------------- self-loop term: out[i] = dis[i]^2 * in[i]; also initializes out ----------------
template <int C>
__global__ __launch_bounds__(256) void k_self_init(const float* __restrict__ in, int ins,
                                                   float* __restrict__ out, int outs,
                                                   const float* __restrict__ dis, int n) {
    constexpr int PER = C / 4;
    long long t = (long long)blockIdx.x * blockDim.x + threadIdx.x;
    if (t >= (long long)n * PER) return;
    int i = (int)(t / PER);
    int f = (int)(t % PER) * 4;
    float d = dis[i];
    float w = d * d;
    float4 v = *(const float4*)(in + (size_t)i * ins + f);
    float4 r;
    r.x = w * v.x; r.y = w * v.y; r.z = w * v.z; r.w = w * v.w;
    *(float4*)(out + (size_t)i * outs + f) = r;
}

// ---------------- per-edge scatter: out[dst] += dis[src]*dis[dst]*in[src] ----------------
template <int C>
__global__ __launch_bounds__(256) void k_edge_agg(const int* __restrict__ ei,  // [2,E] int32
                                                  const float* __restrict__ dis,
                                                  const float* __restrict__ in, int ins,
                                                  float* __restrict__ out, int outs, int E) {
    constexpr int PER = C / 4;
    long long t = (long long)blockIdx.x * blockDim.x + threadIdx.x;
    int e = (int)(t / PER);
    if (e >= E) return;
    int f = (int)(t % PER) * 4;
    int s = ei[e];
    int d = ei[e + E];
    float w = dis[s] * dis[d];
    float4 v = *(const float4*)(in + (size_t)s * ins + f);
    float* o = out + (size_t)d * outs + f;
    atomicAdd(o + 0, w * v.x);
    atomicAdd(o + 1, w * v.y);
    atomicAdd(o + 2, w * v.z);
    atomicAdd(o + 3, w * v.w);
}

// ---------------- bias (+relu) elementwise, in place ----------------
template <int C, bool RELU>
__global__ __launch_bounds__(256) void k_bias_act(float* __restrict__ io, int s,
                                                  const float* __restrict__ bias, int n) {
    constexpr int PER = C / 4;
    long long t = (long long)blockIdx.x * blockDim.x + threadIdx.x;
    if (t >= (long long)n * PER) return;
    int i = (int)(t / PER);
    int f = (int)(t % PER) * 4;
    float4 v = *(float4*)(io + (size_t)i * s + f);
    float4 b = *(const float4*)(bias + f);
    v.x += b.x; v.y += b.y; v.z += b.z; v.w += b.w;
    if (RELU) {
        v.x = fmaxf(v.x, 0.f); v.y = fmaxf(v.y, 0.f);
        v.z = fmaxf(v.z, 0.f); v.w = fmaxf(v.w, 0.f);
    }
    *(float4*)(io + (size_t)i * s + f) = v;
}

// ---------------- fp32 row-tile GEMM: C[M,CN] = A[M,K] @ W[K,CN] (+bias, +relu) ----------------
// One block owns 64 rows and computes ALL CN columns (grid.y == 1), so A and C may
// alias (in-place within the same row-strided buffer): all global A reads complete
// (staged to LDS) before the epilogue writes C, and blocks own disjoint rows.
template <int K, int CN, bool BIAS, bool RELU>
__global__ __launch_bounds__(256) void k_gemm_rt(const float* __restrict__ A, int lda,
                                                 const float* __restrict__ W,
                                                 const float* __restrict__ bias,
                                                 float* __restrict__ Cout, int ldc, int M) {
    constexpr int NJ = CN / 64;  // 64-col chunks per row
    __shared__ __align__(16) float As[16][68];       // As[k][row], padded
    __shared__ __align__(16) float Bs[16][CN + 4];   // Bs[k][col], padded
    const int tid = threadIdx.x;
    const int bm = blockIdx.x * 64;
    const int tx = tid & 15;   // col group
    const int ty = tid >> 4;   // row group (4 rows each)
    const int alr = tid >> 2;          // A-load row 0..63
    const int alk = (tid & 3) << 2;    // A-load k offset 0,4,8,12
    const int blr = tid >> 4;          // B-load k row 0..15
    const int blc = (tid & 15) << 2;   // B-load col 0..60

    float acc[4][NJ][4] = {};

    for (int k0 = 0; k0 < K; k0 += 16) {
        float4 av = make_float4(0.f, 0.f, 0.f, 0.f);
        int arow = bm + alr;
        if (arow < M) av = *(const float4*)(A + (size_t)arow * lda + k0 + alk);
        As[alk + 0][alr] = av.x;
        As[alk + 1][alr] = av.y;
        As[alk + 2][alr] = av.z;
        As[alk + 3][alr] = av.w;
#pragma unroll
        for (int u = 0; u < NJ; ++u) {
            *(float4*)&Bs[blr][blc + u * 64] =
                *(const float4*)(W + (size_t)(k0 + blr) * CN + blc + u * 64);
        }
        __syncthreads();
#pragma unroll
        for (int kk = 0; kk < 16; ++kk) {
            float4 a = *(const float4*)&As[kk][ty << 2];
            float ar[4] = {a.x, a.y, a.z, a.w};
#pragma unroll
            for (int j = 0; j < NJ; ++j) {
                float4 b = *(const float4*)&Bs[kk][j * 64 + (tx << 2)];
#pragma unroll
                for (int i = 0; i < 4; ++i) {
                    acc[i][j][0] += ar[i] * b.x;
                    acc[i][j][1] += ar[i] * b.y;
                    acc[i][j][2] += ar[i] * b.z;
                    acc[i][j][3] += ar[i] * b.w;
                }
            }
        }
        __syncthreads();
    }

#pragma unroll
    for (int i = 0; i < 4; ++i) {
        int row = bm + (ty << 2) + i;
        if (row >= M) continue;
#pragma unroll
        for (int j = 0; j < NJ; ++j) {
            int col = j * 64 + (tx << 2);
            float4 v = {acc[i][j][0], acc[i][j][1], acc[i][j][2], acc[i][j][3]};
            if (BIAS) {
                float4 b = *(const float4*)(bias + col);
                v.x += b.x; v.y += b.y; v.z += b.z; v.w += b.w;
            }
            if (RELU) {
                v.x = fmaxf(v.x, 0.f); v.y = fmaxf(v.y, 0.f);
                v.z = fmaxf(v.z, 0.f); v.w = fmaxf(v.w, 0.f);
            }
            *(float4*)(Cout + (size_t)row * ldc + col) = v;
        }
    }
}

extern "C" void kernel_launch(void* const* d_in, const int* in_sizes, int n_in,
                              void* d_out, int out_size, void* d_ws, size_t ws_size,
                              hipStream_t stream) {
    const float* x  = (const float*)d_in[0];
    const int* ei   = (const int*)d_in[1];   // int32! (JAX x64 disabled)
    const float* W1 = (const float*)d_in[2];
    const float* b1 = (const float*)d_in[3];
    const float* W2 = (const float*)d_in[4];
    const float* b2 = (const float*)d_in[5];
    const float* W3 = (const float*)d_in[6];
    const float* b3 = (const float*)d_in[7];
    float* out = (float*)d_out;

    const int N = in_sizes[0] / 128;  // 100000
    const int E = in_sizes[1] / 2;    // 1600000
    const int* dst = ei + E;

    // workspace: dis[N] | buf[N][256]   (~103 MB total)
    float* dis = (float*)d_ws;
    float* buf = (float*)((char*)d_ws + (((size_t)N * sizeof(float) + 255) & ~(size_t)255));

    // ---- dis = rsqrt(1 + indeg) ----
    k_fill1<<<ceil_div_ll(N, 256), 256, 0, stream>>>(dis, N);
    k_edge_deg<<<ceil_div_ll(E, 256), 256, 0, stream>>>(dst, dis, E);
    k_rsqrt<<<ceil_div_ll(N, 256), 256, 0, stream>>>(dis, N);

    const int gN = ceil_div_ll(N, 64);

    // ---- layer 1: agg1 = A_norm @ x -> buf[:,0:128]; h1 = relu(agg1@W1 + b1) -> buf[:,0:256] (in-place) ----
    k_self_init<128><<<ceil_div_ll((long long)N * 32, 256), 256, 0, stream>>>(x, 128, buf, 256, dis, N);
    k_edge_agg<128><<<ceil_div_ll((long long)E * 32, 256), 256, 0, stream>>>(ei, dis, x, 128, buf, 256, E);
    k_gemm_rt<128, 256, true, true><<<gN, 256, 0, stream>>>(buf, 256, W1, b1, buf, 256, N);

    // ---- layer 2: t2 = h1 @ W2 -> buf[:,0:128] (in-place); agg2 -> buf[:,128:256]; h2 = relu(agg2 + b2) ----
    k_gemm_rt<256, 128, false, false><<<gN, 256, 0, stream>>>(buf, 256, W2, nullptr, buf, 256, N);
    k_self_init<128><<<ceil_div_ll((long long)N * 32, 256), 256, 0, stream>>>(buf, 256, buf + 128, 256, dis, N);
    k_edge_agg<128><<<ceil_div_ll((long long)E * 32, 256), 256, 0, stream>>>(ei, dis, buf, 256, buf + 128, 256, E);
    k_bias_act<128, true><<<ceil_div_ll((long long)N * 32, 256), 256, 0, stream>>>(buf + 128, 256, b2, N);

    // ---- layer 3: t3 = h2 @ W3 -> buf[:,0:64]; out = A_norm @ t3 + b3 ----
    k_gemm_rt<128, 64, false, false><<<gN, 256, 0, stream>>>(buf + 128, 256, W3, nullptr, buf, 256, N);
    k_self_init<64><<<ceil_div_ll((long long)N * 16, 256), 256, 0, stream>>>(buf, 256, out, 64, dis, N);
    k_edge_agg<64><<<ceil_div_ll((long long)E * 16, 256), 256, 0, stream>>>(ei, dis, buf, 256, out, 64, E);
    k_bias_act<64, false><<<ceil_div_ll((long long)N * 16, 256), 256, 0, stream>>>(out, 64, b3, N);
}

// Round 4
// 960.705 us; speedup vs baseline: 7.3756x; 7.3756x over previous
//
#include <hip/hip_runtime.h>

static inline int cdiv(long long a, long long b) { return (int)((a + b - 1) / b); }

// ---------------- CSR build ----------------
__global__ void k_zero_i(int* p, int n) {
    int t = blockIdx.x * blockDim.x + threadIdx.x;
    if (t < n) p[t] = 0;
}

__global__ void k_count(const int* __restrict__ dst, int* __restrict__ deg, int E) {
    int t = blockIdx.x * blockDim.x + threadIdx.x;
    if (t < E) atomicAdd(&deg[dst[t]], 1);
}

__global__ void k_dis(const int* __restrict__ deg, float* __restrict__ dis, int n) {
    int t = blockIdx.x * blockDim.x + threadIdx.x;
    if (t < n) dis[t] = rsqrtf((float)(deg[t] + 1));  // +1 self-loop
}

// single-block exclusive scan of deg[0..n-1] -> row_ptr[0..n]; also cur[i]=row_ptr[i]
__global__ __launch_bounds__(1024) void k_scan(const int* __restrict__ deg,
                                               int* __restrict__ row_ptr,
                                               int* __restrict__ cur, int n) {
    __shared__ int sums[1024];
    const int t = threadIdx.x;
    const int CH = (n + 1024) / 1024;  // 1024*CH >= n+1
    int lo = t * CH;
    int hi = lo + CH;
    if (hi > n + 1) hi = n + 1;
    int s = 0;
    for (int i = lo; i < hi; ++i) s += (i < n) ? deg[i] : 0;
    sums[t] = s;
    __syncthreads();
    for (int off = 1; off < 1024; off <<= 1) {
        int v = (t >= off) ? sums[t - off] : 0;
        __syncthreads();
        sums[t] += v;
        __syncthreads();
    }
    int run = (t == 0) ? 0 : sums[t - 1];
    for (int i = lo; i < hi; ++i) {
        row_ptr[i] = run;
        if (i < n) {
            cur[i] = run;
            run += deg[i];
        }
    }
}

// scatter edges into CSR; store {src, w=dis[src]*dis[dst]} packed per edge
__global__ void k_scatter(const int* __restrict__ ei, const float* __restrict__ dis,
                          int* __restrict__ cur, int2* __restrict__ csr, int E) {
    int e = blockIdx.x * blockDim.x + threadIdx.x;
    if (e >= E) return;
    int s = ei[e];
    int d = ei[e + E];
    float w = dis[s] * dis[d];
    int pos = atomicAdd(&cur[d], 1);
    csr[pos] = make_int2(s, __float_as_int(w));
}

// ---------------- fused aggregation: one wave per output row ----------------
// out[d][:] = (BIAS? b:0) + dis[d]^2*in[d][:] + sum_e w_e * in[src_e][:]; optional ReLU.
// Each output element written exactly once (no atomics).
template <int C, bool BIAS, bool RELU>
__global__ __launch_bounds__(256) void k_agg_csr(const int* __restrict__ row_ptr,
                                                 const int2* __restrict__ csr,
                                                 const float* __restrict__ dis,
                                                 const float* __restrict__ in, int ins,
                                                 float* __restrict__ out, int outs,
                                                 const float* __restrict__ bias, int N) {
    constexpr int VL = C / 64;  // floats per lane (2 for C=128, 1 for C=64)
    const int wave = (int)(((long long)blockIdx.x * blockDim.x + threadIdx.x) >> 6);
    const int lane = threadIdx.x & 63;
    if (wave >= N) return;
    const int d = wave;
    const int c = lane * VL;
    const float dd = dis[d];
    const float wself = dd * dd;

    float acc[VL];
    if (VL == 2) {
        float2 v = *(const float2*)(in + (size_t)d * ins + c);
        acc[0] = wself * v.x;
        acc[1] = wself * v.y;
    } else {
        acc[0] = wself * in[(size_t)d * ins + c];
    }

    int j = row_ptr[d];
    const int hi = row_ptr[d + 1];
    for (; j + 1 < hi; j += 2) {  // unroll 2 for memory-level parallelism
        int2 a = csr[j];
        int2 b = csr[j + 1];
        float wa = __int_as_float(a.y);
        float wb = __int_as_float(b.y);
        if (VL == 2) {
            float2 va = *(const float2*)(in + (size_t)a.x * ins + c);
            float2 vb = *(const float2*)(in + (size_t)b.x * ins + c);
            acc[0] += wa * va.x + wb * vb.x;
            acc[1] += wa * va.y + wb * vb.y;
        } else {
            acc[0] += wa * in[(size_t)a.x * ins + c] + wb * in[(size_t)b.x * ins + c];
        }
    }
    if (j < hi) {
        int2 a = csr[j];
        float wa = __int_as_float(a.y);
        if (VL == 2) {
            float2 va = *(const float2*)(in + (size_t)a.x * ins + c);
            acc[0] += wa * va.x;
            acc[1] += wa * va.y;
        } else {
            acc[0] += wa * in[(size_t)a.x * ins + c];
        }
    }

    if (BIAS) {
        if (VL == 2) {
            float2 b = *(const float2*)(bias + c);
            acc[0] += b.x;
            acc[1] += b.y;
        } else {
            acc[0] += bias[c];
        }
    }
    if (RELU) {
#pragma unroll
        for (int v = 0; v < VL; ++v) acc[v] = fmaxf(acc[v], 0.f);
    }
    if (VL == 2) {
        *(float2*)(out + (size_t)d * outs + c) = make_float2(acc[0], acc[1]);
    } else {
        out[(size_t)d * outs + c] = acc[0];
    }
}

// ---------------- fp32 row-tile GEMM: C[M,CN] = A[M,K] @ W[K,CN] (+bias, +relu) ----------------
// One block owns 64 rows, computes ALL CN columns; epilogue writes after all A reads,
// so A and C may alias row-strided in-place.
template <int K, int CN, bool BIAS, bool RELU>
__global__ __launch_bounds__(256) void k_gemm_rt(const float* __restrict__ A, int lda,
                                                 const float* __restrict__ W,
                                                 const float* __restrict__ bias,
                                                 float* __restrict__ Cout, int ldc, int M) {
    constexpr int NJ = CN / 64;
    __shared__ __align__(16) float As[16][68];
    __shared__ __align__(16) float Bs[16][CN + 4];
    const int tid = threadIdx.x;
    const int bm = blockIdx.x * 64;
    const int tx = tid & 15;
    const int ty = tid >> 4;
    const int alr = tid >> 2;
    const int alk = (tid & 3) << 2;
    const int blr = tid >> 4;
    const int blc = (tid & 15) << 2;

    float acc[4][NJ][4] = {};

    for (int k0 = 0; k0 < K; k0 += 16) {
        float4 av = make_float4(0.f, 0.f, 0.f, 0.f);
        int arow = bm + alr;
        if (arow < M) av = *(const float4*)(A + (size_t)arow * lda + k0 + alk);
        As[alk + 0][alr] = av.x;
        As[alk + 1][alr] = av.y;
        As[alk + 2][alr] = av.z;
        As[alk + 3][alr] = av.w;
#pragma unroll
        for (int u = 0; u < NJ; ++u) {
            *(float4*)&Bs[blr][blc + u * 64] =
                *(const float4*)(W + (size_t)(k0 + blr) * CN + blc + u * 64);
        }
        __syncthreads();
#pragma unroll
        for (int kk = 0; kk < 16; ++kk) {
            float4 a = *(const float4*)&As[kk][ty << 2];
            float ar[4] = {a.x, a.y, a.z, a.w};
#pragma unroll
            for (int j = 0; j < NJ; ++j) {
                float4 b = *(const float4*)&Bs[kk][j * 64 + (tx << 2)];
#pragma unroll
                for (int i = 0; i < 4; ++i) {
                    acc[i][j][0] += ar[i] * b.x;
                    acc[i][j][1] += ar[i] * b.y;
                    acc[i][j][2] += ar[i] * b.z;
                    acc[i][j][3] += ar[i] * b.w;
                }
            }
        }
        __syncthreads();
    }

#pragma unroll
    for (int i = 0; i < 4; ++i) {
        int row = bm + (ty << 2) + i;
        if (row >= M) continue;
#pragma unroll
        for (int j = 0; j < NJ; ++j) {
            int col = j * 64 + (tx << 2);
            float4 v = {acc[i][j][0], acc[i][j][1], acc[i][j][2], acc[i][j][3]};
            if (BIAS) {
                float4 b = *(const float4*)(bias + col);
                v.x += b.x; v.y += b.y; v.z += b.z; v.w += b.w;
            }
            if (RELU) {
                v.x = fmaxf(v.x, 0.f); v.y = fmaxf(v.y, 0.f);
                v.z = fmaxf(v.z, 0.f); v.w = fmaxf(v.w, 0.f);
            }
            *(float4*)(Cout + (size_t)row * ldc + col) = v;
        }
    }
}

extern "C" void kernel_launch(void* const* d_in, const int* in_sizes, int n_in,
                              void* d_out, int out_size, void* d_ws, size_t ws_size,
                              hipStream_t stream) {
    const float* x  = (const float*)d_in[0];
    const int* ei   = (const int*)d_in[1];   // int32 (JAX x64 disabled)
    const float* W1 = (const float*)d_in[2];
    const float* b1 = (const float*)d_in[3];
    const float* W2 = (const float*)d_in[4];
    const float* b2 = (const float*)d_in[5];
    const float* W3 = (const float*)d_in[6];
    const float* b3 = (const float*)d_in[7];
    float* out = (float*)d_out;

    const int N = in_sizes[0] / 128;  // 100000
    const int E = in_sizes[1] / 2;    // 1600000
    const int* dst = ei + E;

    // workspace layout (256B-aligned segments):
    // dis[N] f32 | deg[N] i32 | row_ptr[N+1] i32 | cur[N] i32 | csr[E] int2 | buf[N][256] f32
    char* p = (char*)d_ws;
    auto take = [&](size_t bytes) {
        char* r = p;
        p += (bytes + 255) & ~(size_t)255;
        return r;
    };
    float* dis    = (float*)take((size_t)N * 4);
    int* deg      = (int*)take((size_t)N * 4);
    int* row_ptr  = (int*)take((size_t)(N + 1) * 4);
    int* cur      = (int*)take((size_t)N * 4);
    int2* csr     = (int2*)take((size_t)E * 8);
    float* buf    = (float*)take((size_t)N * 256 * 4);

    // ---- CSR build (reused by all 3 layers) ----
    k_zero_i<<<cdiv(N, 256), 256, 0, stream>>>(deg, N);
    k_count<<<cdiv(E, 256), 256, 0, stream>>>(dst, deg, E);
    k_dis<<<cdiv(N, 256), 256, 0, stream>>>(deg, dis, N);
    k_scan<<<1, 1024, 0, stream>>>(deg, row_ptr, cur, N);
    k_scatter<<<cdiv(E, 256), 256, 0, stream>>>(ei, dis, cur, csr, E);

    const int gN = cdiv(N, 64);                 // GEMM blocks
    const int gA = cdiv((long long)N * 64, 256);  // agg blocks (1 wave/row)

    // ---- layer 1: agg(x) -> buf[:,0:128]; h1 = relu(agg@W1 + b1) -> buf[:,0:256] in-place ----
    k_agg_csr<128, false, false><<<gA, 256, 0, stream>>>(row_ptr, csr, dis, x, 128, buf, 256, nullptr, N);
    k_gemm_rt<128, 256, true, true><<<gN, 256, 0, stream>>>(buf, 256, W1, b1, buf, 256, N);

    // ---- layer 2: t2 = h1@W2 -> buf[:,0:128] in-place; h2 = relu(agg(t2) + b2) -> buf[:,128:256] ----
    k_gemm_rt<256, 128, false, false><<<gN, 256, 0, stream>>>(buf, 256, W2, nullptr, buf, 256, N);
    k_agg_csr<128, true, true><<<gA, 256, 0, stream>>>(row_ptr, csr, dis, buf, 256, buf + 128, 256, b2, N);

    // ---- layer 3: t3 = h2@W3 -> buf[:,0:64]; out = agg(t3) + b3 ----
    k_gemm_rt<128, 64, false, false><<<gN, 256, 0, stream>>>(buf + 128, 256, W3, nullptr, buf, 256, N);
    k_agg_csr<64, true, false><<<gA, 256, 0, stream>>>(row_ptr, csr, dis, buf, 256, out, 64, b3, N);
}

// Round 5
// 691.494 us; speedup vs baseline: 10.2470x; 1.3893x over previous
//
#include <hip/hip_runtime.h>

static inline int cdiv(long long a, long long b) { return (int)((a + b - 1) / b); }

// ---------------- CSR build ----------------
__global__ void k_zero_i(int* p, int n) {
    int t = blockIdx.x * blockDim.x + threadIdx.x;
    if (t < n) p[t] = 0;
}

__global__ void k_count(const int* __restrict__ dst, int* __restrict__ deg, int E) {
    int t = blockIdx.x * blockDim.x + threadIdx.x;
    if (t < E) atomicAdd(&deg[dst[t]], 1);
}

__global__ void k_dis(const int* __restrict__ deg, float* __restrict__ dis, int n) {
    int t = blockIdx.x * blockDim.x + threadIdx.x;
    if (t < n) dis[t] = rsqrtf((float)(deg[t] + 1));  // +1 self-loop
}

// ---- device-wide exclusive scan, 3 phases (N ~ 100k, <= 1024*1024) ----
// phase 1: per-block (1024 elems) inclusive scan -> tmp; block totals -> bsum
__global__ __launch_bounds__(1024) void k_scan1(const int* __restrict__ deg,
                                                int* __restrict__ tmp,
                                                int* __restrict__ bsum, int n) {
    __shared__ int s[1024];
    const int t = threadIdx.x;
    const int i = blockIdx.x * 1024 + t;
    int v = (i < n) ? deg[i] : 0;
    s[t] = v;
    __syncthreads();
    for (int off = 1; off < 1024; off <<= 1) {
        int u = (t >= off) ? s[t - off] : 0;
        __syncthreads();
        s[t] += u;
        __syncthreads();
    }
    if (i < n) tmp[i] = s[t];
    if (t == 1023) bsum[blockIdx.x] = s[1023];
}

// phase 2: single-block inclusive scan of block sums (nb <= 1024)
__global__ __launch_bounds__(1024) void k_scan2(int* __restrict__ bsum, int nb) {
    __shared__ int s[1024];
    const int t = threadIdx.x;
    s[t] = (t < nb) ? bsum[t] : 0;
    __syncthreads();
    for (int off = 1; off < 1024; off <<= 1) {
        int u = (t >= off) ? s[t - off] : 0;
        __syncthreads();
        s[t] += u;
        __syncthreads();
    }
    if (t < nb) bsum[t] = s[t];
}

// phase 3: row_ptr[i] = tmp[i]-deg[i]+offset, cur[i] = row_ptr[i]; row_ptr[n] = total
__global__ __launch_bounds__(1024) void k_scan3(const int* __restrict__ deg,
                                                const int* __restrict__ tmp,
                                                const int* __restrict__ bsum,
                                                int* __restrict__ row_ptr,
                                                int* __restrict__ cur, int n, int nb) {
    const int i = blockIdx.x * 1024 + threadIdx.x;
    if (i < n) {
        int off = (blockIdx.x == 0) ? 0 : bsum[blockIdx.x - 1];
        int r = tmp[i] - deg[i] + off;
        row_ptr[i] = r;
        cur[i] = r;
    } else if (i == n) {
        row_ptr[n] = bsum[nb - 1];
    }
}

// scatter edges into CSR; store {src, w=dis[src]*dis[dst]} packed per edge
__global__ void k_scatter(const int* __restrict__ ei, const float* __restrict__ dis,
                          int* __restrict__ cur, int2* __restrict__ csr, int E) {
    int e = blockIdx.x * blockDim.x + threadIdx.x;
    if (e >= E) return;
    int s = ei[e];
    int d = ei[e + E];
    float w = dis[s] * dis[d];
    int pos = atomicAdd(&cur[d], 1);
    csr[pos] = make_int2(s, __float_as_int(w));
}

// ---------------- fused aggregation: one wave per output row ----------------
// out[d][:] = (BIAS? b:0) + dis[d]^2*in[d][:] + sum_e w_e * in[src_e][:]; optional ReLU.
template <int C, bool BIAS, bool RELU>
__global__ __launch_bounds__(256) void k_agg_csr(const int* __restrict__ row_ptr,
                                                 const int2* __restrict__ csr,
                                                 const float* __restrict__ dis,
                                                 const float* __restrict__ in, int ins,
                                                 float* __restrict__ out, int outs,
                                                 const float* __restrict__ bias, int N) {
    constexpr int VL = C / 64;  // floats per lane (2 for C=128, 1 for C=64)
    const int wave = (int)(((long long)blockIdx.x * blockDim.x + threadIdx.x) >> 6);
    const int lane = threadIdx.x & 63;
    if (wave >= N) return;
    const int d = wave;
    const int c = lane * VL;
    const float dd = dis[d];
    const float wself = dd * dd;

    float acc[VL];
    if (VL == 2) {
        float2 v = *(const float2*)(in + (size_t)d * ins + c);
        acc[0] = wself * v.x;
        acc[1] = wself * v.y;
    } else {
        acc[0] = wself * in[(size_t)d * ins + c];
    }

    int j = row_ptr[d];
    const int hi = row_ptr[d + 1];
    // unroll 4: keep 4 gathers in flight (latency-bound on L2/L3)
    for (; j + 3 < hi; j += 4) {
        int2 e0 = csr[j + 0];
        int2 e1 = csr[j + 1];
        int2 e2 = csr[j + 2];
        int2 e3 = csr[j + 3];
        float w0 = __int_as_float(e0.y), w1 = __int_as_float(e1.y);
        float w2 = __int_as_float(e2.y), w3 = __int_as_float(e3.y);
        if (VL == 2) {
            float2 v0 = *(const float2*)(in + (size_t)e0.x * ins + c);
            float2 v1 = *(const float2*)(in + (size_t)e1.x * ins + c);
            float2 v2 = *(const float2*)(in + (size_t)e2.x * ins + c);
            float2 v3 = *(const float2*)(in + (size_t)e3.x * ins + c);
            acc[0] += w0 * v0.x + w1 * v1.x + w2 * v2.x + w3 * v3.x;
            acc[1] += w0 * v0.y + w1 * v1.y + w2 * v2.y + w3 * v3.y;
        } else {
            acc[0] += w0 * in[(size_t)e0.x * ins + c] + w1 * in[(size_t)e1.x * ins + c] +
                      w2 * in[(size_t)e2.x * ins + c] + w3 * in[(size_t)e3.x * ins + c];
        }
    }
    for (; j < hi; ++j) {
        int2 a = csr[j];
        float wa = __int_as_float(a.y);
        if (VL == 2) {
            float2 va = *(const float2*)(in + (size_t)a.x * ins + c);
            acc[0] += wa * va.x;
            acc[1] += wa * va.y;
        } else {
            acc[0] += wa * in[(size_t)a.x * ins + c];
        }
    }

    if (BIAS) {
        if (VL == 2) {
            float2 b = *(const float2*)(bias + c);
            acc[0] += b.x;
            acc[1] += b.y;
        } else {
            acc[0] += bias[c];
        }
    }
    if (RELU) {
#pragma unroll
        for (int v = 0; v < VL; ++v) acc[v] = fmaxf(acc[v], 0.f);
    }
    if (VL == 2) {
        *(float2*)(out + (size_t)d * outs + c) = make_float2(acc[0], acc[1]);
    } else {
        out[(size_t)d * outs + c] = acc[0];
    }
}

// ---------------- fp32 row-tile GEMM: C[M,CN] = A[M,K] @ W[K,CN] (+bias, +relu) ----------------
// One block owns 64 rows, computes ALL CN columns; epilogue writes after all A reads,
// so A and C may alias row-strided in-place.
template <int K, int CN, bool BIAS, bool RELU>
__global__ __launch_bounds__(256) void k_gemm_rt(const float* __restrict__ A, int lda,
                                                 const float* __restrict__ W,
                                                 const float* __restrict__ bias,
                                                 float* __restrict__ Cout, int ldc, int M) {
    constexpr int NJ = CN / 64;
    __shared__ __align__(16) float As[16][68];
    __shared__ __align__(16) float Bs[16][CN + 4];
    const int tid = threadIdx.x;
    const int bm = blockIdx.x * 64;
    const int tx = tid & 15;
    const int ty = tid >> 4;
    const int alr = tid >> 2;
    const int alk = (tid & 3) << 2;
    const int blr = tid >> 4;
    const int blc = (tid & 15) << 2;

    float acc[4][NJ][4] = {};

    for (int k0 = 0; k0 < K; k0 += 16) {
        float4 av = make_float4(0.f, 0.f, 0.f, 0.f);
        int arow = bm + alr;
        if (arow < M) av = *(const float4*)(A + (size_t)arow * lda + k0 + alk);
        As[alk + 0][alr] = av.x;
        As[alk + 1][alr] = av.y;
        As[alk + 2][alr] = av.z;
        As[alk + 3][alr] = av.w;
#pragma unroll
        for (int u = 0; u < NJ; ++u) {
            *(float4*)&Bs[blr][blc + u * 64] =
                *(const float4*)(W + (size_t)(k0 + blr) * CN + blc + u * 64);
        }
        __syncthreads();
#pragma unroll
        for (int kk = 0; kk < 16; ++kk) {
            float4 a = *(const float4*)&As[kk][ty << 2];
            float ar[4] = {a.x, a.y, a.z, a.w};
#pragma unroll
            for (int j = 0; j < NJ; ++j) {
                float4 b = *(const float4*)&Bs[kk][j * 64 + (tx << 2)];
#pragma unroll
                for (int i = 0; i < 4; ++i) {
                    acc[i][j][0] += ar[i] * b.x;
                    acc[i][j][1] += ar[i] * b.y;
                    acc[i][j][2] += ar[i] * b.z;
                    acc[i][j][3] += ar[i] * b.w;
                }
            }
        }
        __syncthreads();
    }

#pragma unroll
    for (int i = 0; i < 4; ++i) {
        int row = bm + (ty << 2) + i;
        if (row >= M) continue;
#pragma unroll
        for (int j = 0; j < NJ; ++j) {
            int col = j * 64 + (tx << 2);
            float4 v = {acc[i][j][0], acc[i][j][1], acc[i][j][2], acc[i][j][3]};
            if (BIAS) {
                float4 b = *(const float4*)(bias + col);
                v.x += b.x; v.y += b.y; v.z += b.z; v.w += b.w;
            }
            if (RELU) {
                v.x = fmaxf(v.x, 0.f); v.y = fmaxf(v.y, 0.f);
                v.z = fmaxf(v.z, 0.f); v.w = fmaxf(v.w, 0.f);
            }
            *(float4*)(Cout + (size_t)row * ldc + col) = v;
        }
    }
}

extern "C" void kernel_launch(void* const* d_in, const int* in_sizes, int n_in,
                              void* d_out, int out_size, void* d_ws, size_t ws_size,
                              hipStream_t stream) {
    const float* x  = (const float*)d_in[0];
    const int* ei   = (const int*)d_in[1];   // int32 (JAX x64 disabled)
    const float* W1 = (const float*)d_in[2];
    const float* b1 = (const float*)d_in[3];
    const float* W2 = (const float*)d_in[4];
    const float* b2 = (const float*)d_in[5];
    const float* W3 = (const float*)d_in[6];
    const float* b3 = (const float*)d_in[7];
    float* out = (float*)d_out;

    const int N = in_sizes[0] / 128;  // 100000
    const int E = in_sizes[1] / 2;    // 1600000
    const int* dst = ei + E;

    // workspace layout (256B-aligned segments):
    // dis[N] | deg[N] | tmp[N] | bsum[1024] | row_ptr[N+1] | cur[N] | csr[E] int2 | buf[N][256]
    char* p = (char*)d_ws;
    auto take = [&](size_t bytes) {
        char* r = p;
        p += (bytes + 255) & ~(size_t)255;
        return r;
    };
    float* dis   = (float*)take((size_t)N * 4);
    int* deg     = (int*)take((size_t)N * 4);
    int* tmp     = (int*)take((size_t)N * 4);
    int* bsum    = (int*)take((size_t)1024 * 4);
    int* row_ptr = (int*)take((size_t)(N + 1) * 4);
    int* cur     = (int*)take((size_t)N * 4);
    int2* csr    = (int2*)take((size_t)E * 8);
    float* buf   = (float*)take((size_t)N * 256 * 4);

    const int nb = cdiv(N, 1024);  // scan blocks (98 for N=100k)

    // ---- CSR build (reused by all 3 layers) ----
    k_zero_i<<<cdiv(N, 256), 256, 0, stream>>>(deg, N);
    k_count<<<cdiv(E, 256), 256, 0, stream>>>(dst, deg, E);
    k_dis<<<cdiv(N, 256), 256, 0, stream>>>(deg, dis, N);
    k_scan1<<<nb, 1024, 0, stream>>>(deg, tmp, bsum, N);
    k_scan2<<<1, 1024, 0, stream>>>(bsum, nb);
    k_scan3<<<cdiv(N + 1, 1024), 1024, 0, stream>>>(deg, tmp, bsum, row_ptr, cur, N, nb);
    k_scatter<<<cdiv(E, 256), 256, 0, stream>>>(ei, dis, cur, csr, E);

    const int gN = cdiv(N, 64);                   // GEMM blocks
    const int gA = cdiv((long long)N * 64, 256);  // agg blocks (1 wave/row)

    // ---- layer 1: agg(x) -> buf[:,0:128]; h1 = relu(agg@W1 + b1) -> buf[:,0:256] in-place ----
    k_agg_csr<128, false, false><<<gA, 256, 0, stream>>>(row_ptr, csr, dis, x, 128, buf, 256, nullptr, N);
    k_gemm_rt<128, 256, true, true><<<gN, 256, 0, stream>>>(buf, 256, W1, b1, buf, 256, N);

    // ---- layer 2: t2 = h1@W2 -> buf[:,0:128] in-place; h2 = relu(agg(t2) + b2) -> buf[:,128:256] ----
    k_gemm_rt<256, 128, false, false><<<gN, 256, 0, stream>>>(buf, 256, W2, nullptr, buf, 256, N);
    k_agg_csr<128, true, true><<<gA, 256, 0, stream>>>(row_ptr, csr, dis, buf, 256, buf + 128, 256, b2, N);

    // ---- layer 3: t3 = h2@W3 -> buf[:,0:64]; out = agg(t3) + b3 ----
    k_gemm_rt<128, 64, false, false><<<gN, 256, 0, stream>>>(buf + 128, 256, W3, nullptr, buf, 256, N);
    k_agg_csr<64, true, false><<<gA, 256, 0, stream>>>(row_ptr, csr, dis, buf, 256, out, 64, b3, N);
}

// Round 6
// 611.795 us; speedup vs baseline: 11.5819x; 1.1303x over previous
//
#include <hip/hip_runtime.h>
#include <hip/hip_fp16.h>

static inline int cdiv(long long a, long long b) { return (int)((a + b - 1) / b); }

// ---------------- CSR build ----------------
__global__ void k_zero_i(int* p, int n) {
    int t = blockIdx.x * blockDim.x + threadIdx.x;
    if (t < n) p[t] = 0;
}

__global__ void k_count(const int* __restrict__ dst, int* __restrict__ deg, int E) {
    int t = blockIdx.x * blockDim.x + threadIdx.x;
    if (t < E) atomicAdd(&deg[dst[t]], 1);
}

__global__ void k_dis(const int* __restrict__ deg, float* __restrict__ dis, int n) {
    int t = blockIdx.x * blockDim.x + threadIdx.x;
    if (t < n) dis[t] = rsqrtf((float)(deg[t] + 1));  // +1 self-loop
}

// ---- device-wide exclusive scan, 3 phases ----
__global__ __launch_bounds__(1024) void k_scan1(const int* __restrict__ deg,
                                                int* __restrict__ tmp,
                                                int* __restrict__ bsum, int n) {
    __shared__ int s[1024];
    const int t = threadIdx.x;
    const int i = blockIdx.x * 1024 + t;
    int v = (i < n) ? deg[i] : 0;
    s[t] = v;
    __syncthreads();
    for (int off = 1; off < 1024; off <<= 1) {
        int u = (t >= off) ? s[t - off] : 0;
        __syncthreads();
        s[t] += u;
        __syncthreads();
    }
    if (i < n) tmp[i] = s[t];
    if (t == 1023) bsum[blockIdx.x] = s[1023];
}

__global__ __launch_bounds__(1024) void k_scan2(int* __restrict__ bsum, int nb) {
    __shared__ int s[1024];
    const int t = threadIdx.x;
    s[t] = (t < nb) ? bsum[t] : 0;
    __syncthreads();
    for (int off = 1; off < 1024; off <<= 1) {
        int u = (t >= off) ? s[t - off] : 0;
        __syncthreads();
        s[t] += u;
        __syncthreads();
    }
    if (t < nb) bsum[t] = s[t];
}

__global__ __launch_bounds__(1024) void k_scan3(const int* __restrict__ deg,
                                                const int* __restrict__ tmp,
                                                const int* __restrict__ bsum,
                                                int* __restrict__ row_ptr,
                                                int* __restrict__ cur, int n, int nb) {
    const int i = blockIdx.x * 1024 + threadIdx.x;
    if (i < n) {
        int off = (blockIdx.x == 0) ? 0 : bsum[blockIdx.x - 1];
        int r = tmp[i] - deg[i] + off;
        row_ptr[i] = r;
        cur[i] = r;
    } else if (i == n) {
        row_ptr[n] = bsum[nb - 1];
    }
}

__global__ void k_scatter(const int* __restrict__ ei, const float* __restrict__ dis,
                          int* __restrict__ cur, int2* __restrict__ csr, int E) {
    int e = blockIdx.x * blockDim.x + threadIdx.x;
    if (e >= E) return;
    int s = ei[e];
    int d = ei[e + E];
    float w = dis[s] * dis[d];
    int pos = atomicAdd(&cur[d], 1);
    csr[pos] = make_int2(s, __float_as_int(w));
}

// ---------------- fp32 -> fp16 convert (float4 -> 4 halves per thread) ----------------
__global__ __launch_bounds__(256) void k_cvt_h(const float* __restrict__ in,
                                               __half* __restrict__ out, long long n4) {
    long long t = (long long)blockIdx.x * blockDim.x + threadIdx.x;
    if (t >= n4) return;
    float4 v = *(const float4*)(in + t * 4);
    union { float2 f; __half2 h[2]; } u;
    u.h[0] = __floats2half2_rn(v.x, v.y);
    u.h[1] = __floats2half2_rn(v.z, v.w);
    *(float2*)(out + t * 4) = u.f;
}

// ---------------- fused aggregation: one wave per output row ----------------
// out[d][:] = (BIAS? b:0) + dis[d]^2*in[d][:] + sum_e w_e * in[src_e][:]; optional ReLU.
// HIN: gather input stored as fp16 (half the fetch bytes); accumulate fp32.
template <int C, bool BIAS, bool RELU, bool HIN>
__global__ __launch_bounds__(256) void k_agg_csr(const int* __restrict__ row_ptr,
                                                 const int2* __restrict__ csr,
                                                 const float* __restrict__ dis,
                                                 const void* __restrict__ in_, int ins,
                                                 float* __restrict__ out, int outs,
                                                 const float* __restrict__ bias, int N) {
    constexpr int VL = C / 64;  // floats per lane (2 for C=128, 1 for C=64)
    const int wave = (int)(((long long)blockIdx.x * blockDim.x + threadIdx.x) >> 6);
    const int lane = threadIdx.x & 63;
    if (wave >= N) return;
    const int d = wave;
    const int c = lane * VL;
    const float dd = dis[d];
    const float wself = dd * dd;

    auto ld2 = [&](int row) -> float2 {
        if constexpr (HIN) {
            __half2 h = *(const __half2*)((const __half*)in_ + (size_t)row * ins + c);
            return __half22float2(h);
        } else {
            return *(const float2*)((const float*)in_ + (size_t)row * ins + c);
        }
    };
    auto ld1 = [&](int row) -> float {
        if constexpr (HIN) {
            return __half2float(((const __half*)in_)[(size_t)row * ins + c]);
        } else {
            return ((const float*)in_)[(size_t)row * ins + c];
        }
    };

    float acc[VL];
    if (VL == 2) {
        float2 v = ld2(d);
        acc[0] = wself * v.x;
        acc[1] = wself * v.y;
    } else {
        acc[0] = wself * ld1(d);
    }

    int j = row_ptr[d];
    const int hi = row_ptr[d + 1];
    // unroll 4: keep 4 gathers in flight
    for (; j + 3 < hi; j += 4) {
        int2 e0 = csr[j + 0];
        int2 e1 = csr[j + 1];
        int2 e2 = csr[j + 2];
        int2 e3 = csr[j + 3];
        float w0 = __int_as_float(e0.y), w1 = __int_as_float(e1.y);
        float w2 = __int_as_float(e2.y), w3 = __int_as_float(e3.y);
        if (VL == 2) {
            float2 v0 = ld2(e0.x);
            float2 v1 = ld2(e1.x);
            float2 v2 = ld2(e2.x);
            float2 v3 = ld2(e3.x);
            acc[0] += w0 * v0.x + w1 * v1.x + w2 * v2.x + w3 * v3.x;
            acc[1] += w0 * v0.y + w1 * v1.y + w2 * v2.y + w3 * v3.y;
        } else {
            acc[0] += w0 * ld1(e0.x) + w1 * ld1(e1.x) + w2 * ld1(e2.x) + w3 * ld1(e3.x);
        }
    }
    for (; j < hi; ++j) {
        int2 a = csr[j];
        float wa = __int_as_float(a.y);
        if (VL == 2) {
            float2 va = ld2(a.x);
            acc[0] += wa * va.x;
            acc[1] += wa * va.y;
        } else {
            acc[0] += wa * ld1(a.x);
        }
    }

    if (BIAS) {
        if (VL == 2) {
            float2 b = *(const float2*)(bias + c);
            acc[0] += b.x;
            acc[1] += b.y;
        } else {
            acc[0] += bias[c];
        }
    }
    if (RELU) {
#pragma unroll
        for (int v = 0; v < VL; ++v) acc[v] = fmaxf(acc[v], 0.f);
    }
    if (VL == 2) {
        *(float2*)(out + (size_t)d * outs + c) = make_float2(acc[0], acc[1]);
    } else {
        out[(size_t)d * outs + c] = acc[0];
    }
}

// ---------------- fp32 row-tile GEMM: C[M,CN] = A[M,K] @ W[K,CN] (+bias, +relu) ----------------
// One block owns 64 rows, computes ALL CN columns; epilogue writes after all A reads,
// so A and C may alias row-strided in-place (fp32-out path only).
// HOUT: write fp16 output (for gather-only consumers).
template <int K, int CN, bool BIAS, bool RELU, bool HOUT>
__global__ __launch_bounds__(256) void k_gemm_rt(const float* __restrict__ A, int lda,
                                                 const float* __restrict__ W,
                                                 const float* __restrict__ bias,
                                                 void* __restrict__ Cout_, int ldc, int M) {
    constexpr int NJ = CN / 64;
    __shared__ __align__(16) float As[16][68];
    __shared__ __align__(16) float Bs[16][CN + 4];
    const int tid = threadIdx.x;
    const int bm = blockIdx.x * 64;
    const int tx = tid & 15;
    const int ty = tid >> 4;
    const int alr = tid >> 2;
    const int alk = (tid & 3) << 2;
    const int blr = tid >> 4;
    const int blc = (tid & 15) << 2;

    float acc[4][NJ][4] = {};

    for (int k0 = 0; k0 < K; k0 += 16) {
        float4 av = make_float4(0.f, 0.f, 0.f, 0.f);
        int arow = bm + alr;
        if (arow < M) av = *(const float4*)(A + (size_t)arow * lda + k0 + alk);
        As[alk + 0][alr] = av.x;
        As[alk + 1][alr] = av.y;
        As[alk + 2][alr] = av.z;
        As[alk + 3][alr] = av.w;
#pragma unroll
        for (int u = 0; u < NJ; ++u) {
            *(float4*)&Bs[blr][blc + u * 64] =
                *(const float4*)(W + (size_t)(k0 + blr) * CN + blc + u * 64);
        }
        __syncthreads();
#pragma unroll
        for (int kk = 0; kk < 16; ++kk) {
            float4 a = *(const float4*)&As[kk][ty << 2];
            float ar[4] = {a.x, a.y, a.z, a.w};
#pragma unroll
            for (int j = 0; j < NJ; ++j) {
                float4 b = *(const float4*)&Bs[kk][j * 64 + (tx << 2)];
#pragma unroll
                for (int i = 0; i < 4; ++i) {
                    acc[i][j][0] += ar[i] * b.x;
                    acc[i][j][1] += ar[i] * b.y;
                    acc[i][j][2] += ar[i] * b.z;
                    acc[i][j][3] += ar[i] * b.w;
                }
            }
        }
        __syncthreads();
    }

#pragma unroll
    for (int i = 0; i < 4; ++i) {
        int row = bm + (ty << 2) + i;
        if (row >= M) continue;
#pragma unroll
        for (int j = 0; j < NJ; ++j) {
            int col = j * 64 + (tx << 2);
            float4 v = {acc[i][j][0], acc[i][j][1], acc[i][j][2], acc[i][j][3]};
            if (BIAS) {
                float4 b = *(const float4*)(bias + col);
                v.x += b.x; v.y += b.y; v.z += b.z; v.w += b.w;
            }
            if (RELU) {
                v.x = fmaxf(v.x, 0.f); v.y = fmaxf(v.y, 0.f);
                v.z = fmaxf(v.z, 0.f); v.w = fmaxf(v.w, 0.f);
            }
            if constexpr (HOUT) {
                union { float2 f; __half2 h[2]; } u;
                u.h[0] = __floats2half2_rn(v.x, v.y);
                u.h[1] = __floats2half2_rn(v.z, v.w);
                *(float2*)((__half*)Cout_ + (size_t)row * ldc + col) = u.f;
            } else {
                *(float4*)((float*)Cout_ + (size_t)row * ldc + col) = v;
            }
        }
    }
}

extern "C" void kernel_launch(void* const* d_in, const int* in_sizes, int n_in,
                              void* d_out, int out_size, void* d_ws, size_t ws_size,
                              hipStream_t stream) {
    const float* x  = (const float*)d_in[0];
    const int* ei   = (const int*)d_in[1];   // int32 (JAX x64 disabled)
    const float* W1 = (const float*)d_in[2];
    const float* b1 = (const float*)d_in[3];
    const float* W2 = (const float*)d_in[4];
    const float* b2 = (const float*)d_in[5];
    const float* W3 = (const float*)d_in[6];
    const float* b3 = (const float*)d_in[7];
    float* out = (float*)d_out;

    const int N = in_sizes[0] / 128;  // 100000
    const int E = in_sizes[1] / 2;    // 1600000
    const int* dst = ei + E;

    // workspace layout (256B-aligned segments)
    char* base = (char*)d_ws;
    size_t off = 0;
    auto take = [&](size_t bytes) {
        char* r = base + off;
        off += (bytes + 255) & ~(size_t)255;
        return r;
    };
    float* dis   = (float*)take((size_t)N * 4);
    int* deg     = (int*)take((size_t)N * 4);
    int* tmp     = (int*)take((size_t)N * 4);
    int* bsum    = (int*)take((size_t)1024 * 4);
    int* row_ptr = (int*)take((size_t)(N + 1) * 4);
    int* cur     = (int*)take((size_t)N * 4);
    int2* csr    = (int2*)take((size_t)E * 8);
    float* buf   = (float*)take((size_t)N * 256 * 4);
    size_t off_common = off;
    __half* hbuf = (__half*)take((size_t)N * 128 * 2);
    const bool FP16 = (off <= ws_size);  // fall back to fp32 path if ws too small
    (void)off_common;

    const int nb = cdiv(N, 1024);

    // ---- CSR build (reused by all 3 layers) ----
    k_zero_i<<<cdiv(N, 256), 256, 0, stream>>>(deg, N);
    k_count<<<cdiv(E, 256), 256, 0, stream>>>(dst, deg, E);
    k_dis<<<cdiv(N, 256), 256, 0, stream>>>(deg, dis, N);
    k_scan1<<<nb, 1024, 0, stream>>>(deg, tmp, bsum, N);
    k_scan2<<<1, 1024, 0, stream>>>(bsum, nb);
    k_scan3<<<cdiv(N + 1, 1024), 1024, 0, stream>>>(deg, tmp, bsum, row_ptr, cur, N, nb);
    k_scatter<<<cdiv(E, 256), 256, 0, stream>>>(ei, dis, cur, csr, E);

    const int gN = cdiv(N, 64);                   // GEMM blocks
    const int gA = cdiv((long long)N * 64, 256);  // agg blocks (1 wave/row)

    if (FP16) {
        // xh = fp16(x)
        k_cvt_h<<<cdiv((long long)N * 32, 256), 256, 0, stream>>>(x, hbuf, (long long)N * 32);
        // layer 1: agg(xh) -> buf[:,0:128]; h1 = relu(agg@W1+b1) -> buf[:,0:256] in-place
        k_agg_csr<128, false, false, true><<<gA, 256, 0, stream>>>(row_ptr, csr, dis, hbuf, 128, buf, 256, nullptr, N);
        k_gemm_rt<128, 256, true, true, false><<<gN, 256, 0, stream>>>(buf, 256, W1, b1, buf, 256, N);
        // layer 2: t2h = h1@W2 (fp16) -> hbuf; h2 = relu(agg(t2h)+b2) -> buf[:,0:128]
        k_gemm_rt<256, 128, false, false, true><<<gN, 256, 0, stream>>>(buf, 256, W2, nullptr, hbuf, 128, N);
        k_agg_csr<128, true, true, true><<<gA, 256, 0, stream>>>(row_ptr, csr, dis, hbuf, 128, buf, 256, b2, N);
        // layer 3: t3h = h2@W3 (fp16) -> hbuf; out = agg(t3h) + b3
        k_gemm_rt<128, 64, false, false, true><<<gN, 256, 0, stream>>>(buf, 256, W3, nullptr, hbuf, 64, N);
        k_agg_csr<64, true, false, true><<<gA, 256, 0, stream>>>(row_ptr, csr, dis, hbuf, 64, out, 64, b3, N);
    } else {
        // fp32 fallback (round-5 path)
        k_agg_csr<128, false, false, false><<<gA, 256, 0, stream>>>(row_ptr, csr, dis, x, 128, buf, 256, nullptr, N);
        k_gemm_rt<128, 256, true, true, false><<<gN, 256, 0, stream>>>(buf, 256, W1, b1, buf, 256, N);
        k_gemm_rt<256, 128, false, false, false><<<gN, 256, 0, stream>>>(buf, 256, W2, nullptr, buf, 256, N);
        k_agg_csr<128, true, true, false><<<gA, 256, 0, stream>>>(row_ptr, csr, dis, buf, 256, buf + 128, 256, b2, N);
        k_gemm_rt<128, 64, false, false, false><<<gN, 256, 0, stream>>>(buf + 128, 256, W3, nullptr, buf, 256, N);
        k_agg_csr<64, true, false, false><<<gA, 256, 0, stream>>>(row_ptr, csr, dis, buf, 256, out, 64, b3, N);
    }
}

// Round 7
// 481.598 us; speedup vs baseline: 14.7130x; 1.2703x over previous
//
#include <hip/hip_runtime.h>
#include <hip/hip_fp16.h>

static inline int cdiv(long long a, long long b) { return (int)((a + b - 1) / b); }

typedef _Float16 half8 __attribute__((ext_vector_type(8)));
typedef float f32x4 __attribute__((ext_vector_type(4)));

// ---------------- CSR build ----------------
__global__ void k_zero_i(int* p, int n) {
    int t = blockIdx.x * blockDim.x + threadIdx.x;
    if (t < n) p[t] = 0;
}

__global__ void k_count(const int* __restrict__ dst, int* __restrict__ deg, int E) {
    int t = blockIdx.x * blockDim.x + threadIdx.x;
    if (t < E) atomicAdd(&deg[dst[t]], 1);
}

__global__ void k_dis(const int* __restrict__ deg, float* __restrict__ dis, int n) {
    int t = blockIdx.x * blockDim.x + threadIdx.x;
    if (t < n) dis[t] = rsqrtf((float)(deg[t] + 1));  // +1 self-loop
}

__global__ __launch_bounds__(1024) void k_scan1(const int* __restrict__ deg,
                                                int* __restrict__ tmp,
                                                int* __restrict__ bsum, int n) {
    __shared__ int s[1024];
    const int t = threadIdx.x;
    const int i = blockIdx.x * 1024 + t;
    int v = (i < n) ? deg[i] : 0;
    s[t] = v;
    __syncthreads();
    for (int off = 1; off < 1024; off <<= 1) {
        int u = (t >= off) ? s[t - off] : 0;
        __syncthreads();
        s[t] += u;
        __syncthreads();
    }
    if (i < n) tmp[i] = s[t];
    if (t == 1023) bsum[blockIdx.x] = s[1023];
}

__global__ __launch_bounds__(1024) void k_scan2(int* __restrict__ bsum, int nb) {
    __shared__ int s[1024];
    const int t = threadIdx.x;
    s[t] = (t < nb) ? bsum[t] : 0;
    __syncthreads();
    for (int off = 1; off < 1024; off <<= 1) {
        int u = (t >= off) ? s[t - off] : 0;
        __syncthreads();
        s[t] += u;
        __syncthreads();
    }
    if (t < nb) bsum[t] = s[t];
}

__global__ __launch_bounds__(1024) void k_scan3(const int* __restrict__ deg,
                                                const int* __restrict__ tmp,
                                                const int* __restrict__ bsum,
                                                int* __restrict__ row_ptr,
                                                int* __restrict__ cur, int n, int nb) {
    const int i = blockIdx.x * 1024 + threadIdx.x;
    if (i < n) {
        int off = (blockIdx.x == 0) ? 0 : bsum[blockIdx.x - 1];
        int r = tmp[i] - deg[i] + off;
        row_ptr[i] = r;
        cur[i] = r;
    } else if (i == n) {
        row_ptr[n] = bsum[nb - 1];
    }
}

__global__ void k_scatter(const int* __restrict__ ei, const float* __restrict__ dis,
                          int* __restrict__ cur, int2* __restrict__ csr, int E) {
    int e = blockIdx.x * blockDim.x + threadIdx.x;
    if (e >= E) return;
    int s = ei[e];
    int d = ei[e + E];
    float w = dis[s] * dis[d];
    int pos = atomicAdd(&cur[d], 1);
    csr[pos] = make_int2(s, __float_as_int(w));
}

// ---------------- fp32 -> fp16 convert ----------------
__global__ __launch_bounds__(256) void k_cvt_h(const float* __restrict__ in,
                                               __half* __restrict__ out, long long n4) {
    long long t = (long long)blockIdx.x * blockDim.x + threadIdx.x;
    if (t >= n4) return;
    float4 v = *(const float4*)(in + t * 4);
    union { float2 f; __half2 h[2]; } u;
    u.h[0] = __floats2half2_rn(v.x, v.y);
    u.h[1] = __floats2half2_rn(v.z, v.w);
    *(float2*)(out + t * 4) = u.f;
}

// ---------------- weight prep: W fp32 [K][CN] -> swizzled fp16 W^T [CN][K] ----------------
// 16B chunk (8 halves of row n = 8 consecutive k) stored at byte n*2K + ((c*16) ^ ((n&7)<<4))
template <int K, int CN>
__global__ void k_prep_wt(const float* __restrict__ W, char* __restrict__ wt) {
    constexpr int CH = K / 8;
    int id = blockIdx.x * blockDim.x + threadIdx.x;
    if (id >= CN * CH) return;
    int n = id / CH, c = id % CH;
    half8 h;
#pragma unroll
    for (int j = 0; j < 8; ++j) h[j] = (_Float16)W[(size_t)(c * 8 + j) * CN + n];
    *(half8*)(wt + (size_t)n * (2 * K) + ((c * 16) ^ ((n & 7) << 4))) = h;
}

// ---------------- fused aggregation: one wave per output row ----------------
// out[d][:] = (BIAS? b:0) + dis[d]^2*in[d][:] + sum_e w_e*in[src_e][:]; optional ReLU.
// HIN/HOUT: fp16 input / output.
template <int C, bool BIAS, bool RELU, bool HIN, bool HOUT>
__global__ __launch_bounds__(256) void k_agg_csr(const int* __restrict__ row_ptr,
                                                 const int2* __restrict__ csr,
                                                 const float* __restrict__ dis,
                                                 const void* __restrict__ in_, int ins,
                                                 void* __restrict__ out_, int outs,
                                                 const float* __restrict__ bias, int N) {
    constexpr int VL = C / 64;  // floats per lane (2 for C=128, 1 for C=64)
    const int wave = (int)(((long long)blockIdx.x * blockDim.x + threadIdx.x) >> 6);
    const int lane = threadIdx.x & 63;
    if (wave >= N) return;
    const int d = wave;
    const int c = lane * VL;
    const float dd = dis[d];
    const float wself = dd * dd;

    auto ld2 = [&](int row) -> float2 {
        if constexpr (HIN) {
            __half2 h = *(const __half2*)((const __half*)in_ + (size_t)row * ins + c);
            return __half22float2(h);
        } else {
            return *(const float2*)((const float*)in_ + (size_t)row * ins + c);
        }
    };
    auto ld1 = [&](int row) -> float {
        if constexpr (HIN) {
            return __half2float(((const __half*)in_)[(size_t)row * ins + c]);
        } else {
            return ((const float*)in_)[(size_t)row * ins + c];
        }
    };

    float acc[VL];
    if (VL == 2) {
        float2 v = ld2(d);
        acc[0] = wself * v.x;
        acc[1] = wself * v.y;
    } else {
        acc[0] = wself * ld1(d);
    }

    int j = row_ptr[d];
    const int hi = row_ptr[d + 1];
    for (; j + 3 < hi; j += 4) {
        int2 e0 = csr[j + 0];
        int2 e1 = csr[j + 1];
        int2 e2 = csr[j + 2];
        int2 e3 = csr[j + 3];
        float w0 = __int_as_float(e0.y), w1 = __int_as_float(e1.y);
        float w2 = __int_as_float(e2.y), w3 = __int_as_float(e3.y);
        if (VL == 2) {
            float2 v0 = ld2(e0.x);
            float2 v1 = ld2(e1.x);
            float2 v2 = ld2(e2.x);
            float2 v3 = ld2(e3.x);
            acc[0] += w0 * v0.x + w1 * v1.x + w2 * v2.x + w3 * v3.x;
            acc[1] += w0 * v0.y + w1 * v1.y + w2 * v2.y + w3 * v3.y;
        } else {
            acc[0] += w0 * ld1(e0.x) + w1 * ld1(e1.x) + w2 * ld1(e2.x) + w3 * ld1(e3.x);
        }
    }
    for (; j < hi; ++j) {
        int2 a = csr[j];
        float wa = __int_as_float(a.y);
        if (VL == 2) {
            float2 va = ld2(a.x);
            acc[0] += wa * va.x;
            acc[1] += wa * va.y;
        } else {
            acc[0] += wa * ld1(a.x);
        }
    }

    if (BIAS) {
        if (VL == 2) {
            float2 b = *(const float2*)(bias + c);
            acc[0] += b.x;
            acc[1] += b.y;
        } else {
            acc[0] += bias[c];
        }
    }
    if (RELU) {
#pragma unroll
        for (int v = 0; v < VL; ++v) acc[v] = fmaxf(acc[v], 0.f);
    }
    if constexpr (HOUT) {
        if (VL == 2) {
            *(__half2*)((__half*)out_ + (size_t)d * outs + c) = __floats2half2_rn(acc[0], acc[1]);
        } else {
            ((__half*)out_)[(size_t)d * outs + c] = __float2half(acc[0]);
        }
    } else {
        if (VL == 2) {
            *(float2*)((float*)out_ + (size_t)d * outs + c) = make_float2(acc[0], acc[1]);
        } else {
            ((float*)out_)[(size_t)d * outs + c] = acc[0];
        }
    }
}

// ---------------- fp16 MFMA GEMM: C[M,CN] = A[M,K] @ W[K,CN] (+bias,+relu), fp16 out ----
// Whole W^T (fp16, swizzled) staged in LDS per block. Block = 4 waves x 32 rows = 128 rows.
// Per wave: 2 strips of 16 rows; A frags held in registers across all n-tiles.
// mfma(Wfrag, Afrag): output m = lane&15, n = j*16 + (lane>>4)*4 + reg.
template <int K, int CN, bool BIAS, bool RELU>
__global__ __launch_bounds__(256) void k_gemm_mfma(const _Float16* __restrict__ A,
                                                   const char* __restrict__ wt,
                                                   const float* __restrict__ bias,
                                                   _Float16* __restrict__ C, int M) {
    constexpr int T = K / 32;    // MFMA k-steps
    constexpr int NT = CN / 16;  // n-tiles
    __shared__ __align__(16) char wlds[CN * K * 2];
    const int tid = threadIdx.x;
    for (int i = tid; i < CN * K / 8; i += 256)
        ((float4*)wlds)[i] = ((const float4*)wt)[i];
    __syncthreads();

    const int l = tid & 63;
    const int w = tid >> 6;
    const int r0 = blockIdx.x * 128 + w * 32;
    const int lm = l & 15;
    const int lg = l >> 4;  // 0..3
    const int sw = (l & 7) << 4;

    // A fragments: strip s rows r0+s*16+lm, k = t*32 + lg*8 + 0..7
    half8 af[2][T];
#pragma unroll
    for (int s = 0; s < 2; ++s) {
        int row = r0 + s * 16 + lm;
        row = row < M ? row : M - 1;
        const _Float16* ap = A + (size_t)row * K + lg * 8;
#pragma unroll
        for (int t = 0; t < T; ++t) af[s][t] = *(const half8*)(ap + t * 32);
    }

    f32x4 acc[2][NT] = {};
#pragma unroll
    for (int j = 0; j < NT; ++j) {
        const int n = j * 16 + lm;
        const char* bp = wlds + n * (2 * K);
        half8 bf[T];
#pragma unroll
        for (int t = 0; t < T; ++t)
            bf[t] = *(const half8*)(bp + ((t * 64 + lg * 16) ^ sw));
#pragma unroll
        for (int s = 0; s < 2; ++s)
#pragma unroll
            for (int t = 0; t < T; ++t)
                acc[s][j] = __builtin_amdgcn_mfma_f32_16x16x32_f16(bf[t], af[s][t], acc[s][j], 0, 0, 0);
    }

#pragma unroll
    for (int s = 0; s < 2; ++s) {
        const int m = r0 + s * 16 + lm;
        if (m >= M) continue;
#pragma unroll
        for (int j = 0; j < NT; ++j) {
            const int n0 = j * 16 + lg * 4;
            f32x4 v = acc[s][j];
            if (BIAS) {
                float4 b = *(const float4*)(bias + n0);
                v[0] += b.x; v[1] += b.y; v[2] += b.z; v[3] += b.w;
            }
            if (RELU) {
                v[0] = fmaxf(v[0], 0.f); v[1] = fmaxf(v[1], 0.f);
                v[2] = fmaxf(v[2], 0.f); v[3] = fmaxf(v[3], 0.f);
            }
            union { float2 f; __half2 h[2]; } u;
            u.h[0] = __floats2half2_rn(v[0], v[1]);
            u.h[1] = __floats2half2_rn(v[2], v[3]);
            *(float2*)(C + (size_t)m * CN + n0) = u.f;
        }
    }
}

extern "C" void kernel_launch(void* const* d_in, const int* in_sizes, int n_in,
                              void* d_out, int out_size, void* d_ws, size_t ws_size,
                              hipStream_t stream) {
    const float* x  = (const float*)d_in[0];
    const int* ei   = (const int*)d_in[1];   // int32 (JAX x64 disabled)
    const float* W1 = (const float*)d_in[2];
    const float* b1 = (const float*)d_in[3];
    const float* W2 = (const float*)d_in[4];
    const float* b2 = (const float*)d_in[5];
    const float* W3 = (const float*)d_in[6];
    const float* b3 = (const float*)d_in[7];
    float* out = (float*)d_out;

    const int N = in_sizes[0] / 128;  // 100000
    const int E = in_sizes[1] / 2;    // 1600000
    const int* dst = ei + E;

    // workspace (256B-aligned segments), ~181 MB total
    char* base = (char*)d_ws;
    size_t off = 0;
    auto take = [&](size_t bytes) {
        char* r = base + off;
        off += (bytes + 255) & ~(size_t)255;
        return r;
    };
    float* dis     = (float*)take((size_t)N * 4);
    int* deg       = (int*)take((size_t)N * 4);
    int* tmp       = (int*)take((size_t)N * 4);
    int* bsum      = (int*)take((size_t)1024 * 4);
    int* row_ptr   = (int*)take((size_t)(N + 1) * 4);
    int* cur       = (int*)take((size_t)N * 4);
    int2* csr      = (int2*)take((size_t)E * 8);
    _Float16* xh   = (_Float16*)take((size_t)N * 128 * 2);
    _Float16* a1   = (_Float16*)take((size_t)N * 128 * 2);
    _Float16* h1   = (_Float16*)take((size_t)N * 256 * 2);
    _Float16* t2   = (_Float16*)take((size_t)N * 128 * 2);
    _Float16* h2   = (_Float16*)take((size_t)N * 128 * 2);
    _Float16* t3   = (_Float16*)take((size_t)N * 64 * 2);
    char* wt1      = take(256 * 128 * 2);
    char* wt2      = take(128 * 256 * 2);
    char* wt3      = take(64 * 128 * 2);

    const int nb = cdiv(N, 1024);

    // ---- CSR build (reused by all 3 layers) ----
    k_zero_i<<<cdiv(N, 256), 256, 0, stream>>>(deg, N);
    k_count<<<cdiv(E, 256), 256, 0, stream>>>(dst, deg, E);
    k_dis<<<cdiv(N, 256), 256, 0, stream>>>(deg, dis, N);
    k_scan1<<<nb, 1024, 0, stream>>>(deg, tmp, bsum, N);
    k_scan2<<<1, 1024, 0, stream>>>(bsum, nb);
    k_scan3<<<cdiv(N + 1, 1024), 1024, 0, stream>>>(deg, tmp, bsum, row_ptr, cur, N, nb);
    k_scatter<<<cdiv(E, 256), 256, 0, stream>>>(ei, dis, cur, csr, E);

    // ---- prep: x -> fp16; weights -> swizzled fp16 W^T ----
    k_cvt_h<<<cdiv((long long)N * 32, 256), 256, 0, stream>>>(x, (__half*)xh, (long long)N * 32);
    k_prep_wt<128, 256><<<cdiv(256 * 16, 256), 256, 0, stream>>>(W1, wt1);
    k_prep_wt<256, 128><<<cdiv(128 * 32, 256), 256, 0, stream>>>(W2, wt2);
    k_prep_wt<128, 64><<<cdiv(64 * 16, 256), 256, 0, stream>>>(W3, wt3);

    const int gA = cdiv((long long)N * 64, 256);  // agg: 1 wave/row
    const int gG = cdiv(N, 128);                  // gemm: 128 rows/block

    // ---- layer 1: a1 = agg(xh); h1 = relu(a1@W1 + b1) ----
    k_agg_csr<128, false, false, true, true><<<gA, 256, 0, stream>>>(row_ptr, csr, dis, xh, 128, a1, 128, nullptr, N);
    k_gemm_mfma<128, 256, true, true><<<gG, 256, 0, stream>>>(a1, wt1, b1, h1, N);

    // ---- layer 2: t2 = h1@W2; h2 = relu(agg(t2) + b2) ----
    k_gemm_mfma<256, 128, false, false><<<gG, 256, 0, stream>>>(h1, wt2, nullptr, t2, N);
    k_agg_csr<128, true, true, true, true><<<gA, 256, 0, stream>>>(row_ptr, csr, dis, t2, 128, h2, 128, b2, N);

    // ---- layer 3: t3 = h2@W3; out = agg(t3) + b3 ----
    k_gemm_mfma<128, 64, false, false><<<gG, 256, 0, stream>>>(h2, wt3, nullptr, t3, N);
    k_agg_csr<64, true, false, true, false><<<gA, 256, 0, stream>>>(row_ptr, csr, dis, t3, 64, out, 64, b3, N);
}